// Round 1
// baseline (237.542 us; speedup 1.0000x reference)
//
#include <hip/hip_runtime.h>
#include <math.h>

#define DIM 32
#define NK  16

// ---------------------------------------------------------------------------
// Setup: precompute per-expert Gaussian constants into workspace.
//   ws[0 .. NK*DIM-1]      : h[k][d]   = -0.5 / sigma2[k][d]
//   ws[NK*DIM .. +NK-1]    : cconst[k] = rsqrt( prod_d 2*pi*sigma2[k][d] )
// Re-run every launch (d_ws is re-poisoned by the harness).
// ---------------------------------------------------------------------------
__global__ __launch_bounds__(64) void gmm_setup_kernel(
    const float* __restrict__ logsigma, float* __restrict__ ws)
{
  int i = threadIdx.x + blockIdx.x * 64;
  if (i < NK * DIM) {
    float s2 = expf(2.0f * logsigma[i]);
    ws[i] = -0.5f / s2;
  }
  if (i < NK) {
    float p = 1.0f;
    #pragma unroll
    for (int d = 0; d < DIM; ++d) {
      float s2 = expf(2.0f * logsigma[i * DIM + d]);
      p *= 6.283185307179586f * s2;
    }
    ws[NK * DIM + i] = rsqrtf(p);
  }
}

// ---------------------------------------------------------------------------
// Main kernel: one thread = one sample.
//   out[b] = ( sum_k ps_k * relu(x W_k^T + b_k) ) / ( sum_k ps_k )
// ps_k is consumed in the iteration that produces it -> no ps[] array, no LDS.
// All weight accesses are wave-uniform (k uniform, o/d compile-time) ->
// scalar loads; VALU does ~19K fma-class ops/thread.
// ---------------------------------------------------------------------------
__global__ __launch_bounds__(256) void gmm_moe_kernel(
    const float* __restrict__ x,
    const float* __restrict__ mu,
    const float* __restrict__ W,
    const float* __restrict__ bias,
    const float* __restrict__ ws,   // h[NK*DIM] then cconst[NK]
    float* __restrict__ out,
    int B)
{
  const int b = blockIdx.x * 256 + threadIdx.x;
  if (b >= B) return;

  const float* __restrict__ h      = ws;
  const float* __restrict__ cconst = ws + NK * DIM;

  // x row -> registers (8 x float4, contiguous 128B per thread)
  float xr[DIM];
  {
    const float4* __restrict__ xv =
        reinterpret_cast<const float4*>(x + (size_t)b * DIM);
    #pragma unroll
    for (int j = 0; j < DIM / 4; ++j) {
      float4 v = xv[j];
      xr[4*j+0] = v.x; xr[4*j+1] = v.y; xr[4*j+2] = v.z; xr[4*j+3] = v.w;
    }
  }

  float acc[DIM];
  #pragma unroll
  for (int o = 0; o < DIM; ++o) acc[o] = 0.0f;
  float sum = 0.0f;

  for (int k = 0; k < NK; ++k) {           // runtime loop: compact code, k in SGPR
    // --- Gaussian gate numerator: p = const_k * exp( sum_d diff^2 * (-0.5/s2) )
    float e = 0.0f;
    #pragma unroll
    for (int d = 0; d < DIM; ++d) {
      float diff = xr[d] - mu[k * DIM + d];
      e = fmaf(diff * diff, h[k * DIM + d], e);
    }
    float p = cconst[k] * __expf(e);
    sum += p;

    // --- expert linear + ReLU, gate-weighted accumulate (unnormalized)
    #pragma unroll
    for (int o = 0; o < DIM; ++o) {
      float s = bias[k * DIM + o];
      #pragma unroll
      for (int d = 0; d < DIM; ++d) {
        s = fmaf(xr[d], W[(k * DIM + o) * DIM + d], s);
      }
      acc[o] = fmaf(p, fmaxf(s, 0.0f), acc[o]);
    }
  }

  const float invsum = 1.0f / sum;

  {
    float4* __restrict__ ov = reinterpret_cast<float4*>(out + (size_t)b * DIM);
    #pragma unroll
    for (int j = 0; j < DIM / 4; ++j) {
      float4 v;
      v.x = acc[4*j+0] * invsum;
      v.y = acc[4*j+1] * invsum;
      v.z = acc[4*j+2] * invsum;
      v.w = acc[4*j+3] * invsum;
      ov[j] = v;
    }
  }
}

extern "C" void kernel_launch(void* const* d_in, const int* in_sizes, int n_in,
                              void* d_out, int out_size, void* d_ws, size_t ws_size,
                              hipStream_t stream) {
  const float* x  = (const float*)d_in[0];   // [B, DIM]
  const float* mu = (const float*)d_in[1];   // [NK, DIM]
  const float* ls = (const float*)d_in[2];   // [NK, DIM]
  const float* W  = (const float*)d_in[3];   // [NK, DIM, DIM]
  const float* bv = (const float*)d_in[4];   // [NK, DIM]
  float* out = (float*)d_out;                // [B, DIM]
  float* ws  = (float*)d_ws;                 // needs (NK*DIM + NK) floats

  const int B = in_sizes[0] / DIM;

  gmm_setup_kernel<<<(NK * DIM + 63) / 64, 64, 0, stream>>>(ls, ws);
  gmm_moe_kernel<<<(B + 255) / 256, 256, 0, stream>>>(x, mu, W, bv, ws, out, B);
}

// Round 2
// 116.105 us; speedup vs baseline: 2.0459x; 2.0459x over previous
//
#include <hip/hip_runtime.h>
#include <math.h>

#define DIM 32
#define NK  16
#define LOG2E 1.4426950408889634f

typedef __attribute__((ext_vector_type(8))) short bf16x8;
typedef __attribute__((ext_vector_type(4))) float f32x4;

#define MFMA16 __builtin_amdgcn_mfma_f32_16x16x32_bf16

// ws byte layout (all precomputed by gmm_setup_kernel each launch):
#define WHI_OFF 0        // [NK][DIM][DIM] bf16 hi of W        (32768 B)
#define WLO_OFF 32768    // [NK][DIM][DIM] bf16 lo of W        (32768 B)
#define HH_OFF  65536    // [NK][DIM] bf16 hi of h*log2e       (1024 B)
#define HL_OFF  66560    // [NK][DIM] bf16 lo
#define GH_OFF  67584    // [NK][DIM] bf16 hi of (mu/s2)*log2e
#define GL_OFF  68608    // [NK][DIM] bf16 lo
#define CG_OFF  69632    // [NK] f32: log2(const_k) + sum(mu^2*h)*log2e

// Truncation split: x ~= hi + lo with ~17 mantissa bits kept.
__device__ __forceinline__ void split2(float x, short* hi, short* lo) {
  unsigned u = __float_as_uint(x);
  *hi = (short)(u >> 16);
  float hf = __uint_as_float(u & 0xFFFF0000u);
  float l = x - hf;                       // exact (low bits of x)
  *lo = (short)(__float_as_uint(l) >> 16);
}

__global__ __launch_bounds__(256) void gmm_setup_kernel(
    const float* __restrict__ mu, const float* __restrict__ logsigma,
    const float* __restrict__ W, char* __restrict__ ws)
{
  int i = blockIdx.x * 256 + threadIdx.x;
  short* whi = (short*)(ws + WHI_OFF);
  short* wlo = (short*)(ws + WLO_OFF);
  if (i < NK * DIM * DIM) split2(W[i], &whi[i], &wlo[i]);
  if (i < NK * DIM) {
    float s2 = __expf(2.0f * logsigma[i]);
    float h = (-0.5f / s2) * LOG2E;       // log2e folded in: exp2 later
    float g = (mu[i] / s2) * LOG2E;       // = -2*mu*h*log2e
    short a, b;
    split2(h, &a, &b);
    ((short*)(ws + HH_OFF))[i] = a; ((short*)(ws + HL_OFF))[i] = b;
    split2(g, &a, &b);
    ((short*)(ws + GH_OFF))[i] = a; ((short*)(ws + GL_OFF))[i] = b;
  }
  if (i < NK) {
    float acc = 0.0f;
    for (int d = 0; d < DIM; ++d) {
      float s2 = __expf(2.0f * logsigma[i * DIM + d]);
      float m  = mu[i * DIM + d];
      // log2(const) contribution - 0.5*log2(2*pi*s2); plus mu^2*h*log2e
      acc += m * m * (-0.5f / s2) * LOG2E - 0.5f * log2f(6.283185307179586f * s2);
    }
    ((float*)(ws + CG_OFF))[i] = acc;
  }
}

// One wave = 64 samples = 4 tiles of 16. mfma_f32_16x16x32_bf16:
//   A: row = lane%16, k = (lane/16)*8 + j   (x tile, K=32 dims)
//   B: col = lane%16, k = (lane/16)*8 + j   (W^T / gate matrices)
//   D: col = lane&15, row = (lane>>4)*4 + reg   [m89-verified]
__global__ __launch_bounds__(256, 4) void gmm_moe_kernel(
    const float* __restrict__ x,
    const float* __restrict__ bias,
    const char* __restrict__ ws,
    float* __restrict__ out)
{
  __shared__ float lds_p[4][4][NK][16];   // [wave][tile][expert][sample] gate w
  const int wid  = threadIdx.x >> 6;
  const int lane = threadIdx.x & 63;
  const int g = lane >> 4;                // k-chunk / row-group
  const int c = lane & 15;                // A-row (sample) & B-col index
  const int sbase = (blockIdx.x * 4 + wid) * 64;

  const bf16x8* whi = (const bf16x8*)(ws + WHI_OFF);
  const bf16x8* wlo = (const bf16x8*)(ws + WLO_OFF);
  const bf16x8 fhh = ((const bf16x8*)(ws + HH_OFF))[c * 4 + g];
  const bf16x8 fhl = ((const bf16x8*)(ws + HL_OFF))[c * 4 + g];
  const bf16x8 fgh = ((const bf16x8*)(ws + GH_OFF))[c * 4 + g];
  const bf16x8 fgl = ((const bf16x8*)(ws + GL_OFF))[c * 4 + g];
  const float  cgv = ((const float*)(ws + CG_OFF))[c];

  bf16x8 xh[4], xl[4];

  // ---- Gate phase: exponent via split-bf16 MFMA, exp2, row-sum, normalize ----
  #pragma unroll
  for (int t = 0; t < 4; ++t) {
    const float* xp = x + (size_t)(sbase + t * 16 + c) * DIM + g * 8;
    float4 a0 = ((const float4*)xp)[0];
    float4 a1 = ((const float4*)xp)[1];
    float xv[8] = {a0.x, a0.y, a0.z, a0.w, a1.x, a1.y, a1.z, a1.w};
    bf16x8 x2h, x2l;
    #pragma unroll
    for (int j = 0; j < 8; ++j) {
      short h_, l_;
      split2(xv[j], &h_, &l_);
      xh[t][j] = h_; xl[t][j] = l_;
      float q = xv[j] * xv[j];
      split2(q, &h_, &l_);
      x2h[j] = h_; x2l[j] = l_;
    }
    f32x4 e = {cgv, cgv, cgv, cgv};
    e = MFMA16(x2h,   fhh, e, 0, 0, 0);
    e = MFMA16(x2l,   fhh, e, 0, 0, 0);
    e = MFMA16(x2h,   fhl, e, 0, 0, 0);
    e = MFMA16(xh[t], fgh, e, 0, 0, 0);
    e = MFMA16(xl[t], fgh, e, 0, 0, 0);
    e = MFMA16(xh[t], fgl, e, 0, 0, 0);
    // e[r] = log2(p) for sample (g*4+r), expert c
    float pr[4], sr[4];
    #pragma unroll
    for (int r = 0; r < 4; ++r) {
      pr[r] = __builtin_amdgcn_exp2f(e[r]);
      float s = pr[r];
      s += __shfl_xor(s, 1, 64);
      s += __shfl_xor(s, 2, 64);
      s += __shfl_xor(s, 4, 64);
      s += __shfl_xor(s, 8, 64);          // sum over the 16 experts
      sr[r] = s;
    }
    f32x4 wv;
    #pragma unroll
    for (int r = 0; r < 4; ++r) wv[r] = pr[r] * __builtin_amdgcn_rcpf(sr[r]);
    *(f32x4*)&lds_p[wid][t][c][g * 4] = wv;   // transpose for epilogue reads
  }

  // ---- Expert loop: C = relu(x W_k^T + b_k), out += w_k * C ----
  f32x4 o0[4], o1[4];
  #pragma unroll
  for (int t = 0; t < 4; ++t) { o0[t] = (f32x4){0,0,0,0}; o1[t] = (f32x4){0,0,0,0}; }

  for (int k = 0; k < NK; ++k) {
    bf16x8 w0h = whi[(k * DIM +      c) * 4 + g];
    bf16x8 w0l = wlo[(k * DIM +      c) * 4 + g];
    bf16x8 w1h = whi[(k * DIM + 16 + c) * 4 + g];
    bf16x8 w1l = wlo[(k * DIM + 16 + c) * 4 + g];
    float b0 = bias[k * DIM + c];
    float b1 = bias[k * DIM + 16 + c];
    #pragma unroll
    for (int t = 0; t < 4; ++t) {
      f32x4 s0 = {b0, b0, b0, b0}, s1 = {b1, b1, b1, b1};
      s0 = MFMA16(xh[t], w0h, s0, 0, 0, 0);
      s0 = MFMA16(xl[t], w0h, s0, 0, 0, 0);
      s0 = MFMA16(xh[t], w0l, s0, 0, 0, 0);
      s1 = MFMA16(xh[t], w1h, s1, 0, 0, 0);
      s1 = MFMA16(xl[t], w1h, s1, 0, 0, 0);
      s1 = MFMA16(xh[t], w1l, s1, 0, 0, 0);
      f32x4 wv = *(const f32x4*)&lds_p[wid][t][k][g * 4];
      #pragma unroll
      for (int r = 0; r < 4; ++r) {
        o0[t][r] = fmaf(wv[r], fmaxf(s0[r], 0.0f), o0[t][r]);
        o1[t][r] = fmaf(wv[r], fmaxf(s1[r], 0.0f), o1[t][r]);
      }
    }
  }

  // ---- Store: lane (g,c) holds rows g*4+r of each tile, cols c and c+16 ----
  #pragma unroll
  for (int t = 0; t < 4; ++t) {
    #pragma unroll
    for (int r = 0; r < 4; ++r) {
      size_t row = (size_t)(sbase + t * 16 + g * 4 + r);
      out[row * DIM + c]      = o0[t][r];
      out[row * DIM + 16 + c] = o1[t][r];
    }
  }
}

extern "C" void kernel_launch(void* const* d_in, const int* in_sizes, int n_in,
                              void* d_out, int out_size, void* d_ws, size_t ws_size,
                              hipStream_t stream) {
  const float* x  = (const float*)d_in[0];   // [B, DIM]
  const float* mu = (const float*)d_in[1];   // [NK, DIM]
  const float* ls = (const float*)d_in[2];   // [NK, DIM]
  const float* W  = (const float*)d_in[3];   // [NK, DIM, DIM]
  const float* bv = (const float*)d_in[4];   // [NK, DIM]
  float* out = (float*)d_out;
  const int B = in_sizes[0] / DIM;

  gmm_setup_kernel<<<(NK * DIM * DIM + 255) / 256, 256, 0, stream>>>(
      mu, ls, W, (char*)d_ws);
  gmm_moe_kernel<<<B / 256, 256, 0, stream>>>(x, bv, (const char*)d_ws, out);
}

// Round 3
// 114.898 us; speedup vs baseline: 2.0674x; 1.0105x over previous
//
#include <hip/hip_runtime.h>
#include <math.h>

#define DIM 32
#define NK  16
#define LOG2E 1.4426950408889634f

typedef __attribute__((ext_vector_type(8))) short bf16x8;
typedef __attribute__((ext_vector_type(4))) float f32x4;

#define MFMA16 __builtin_amdgcn_mfma_f32_16x16x32_bf16

// ws byte layout (precomputed by gmm_setup_kernel each launch):
#define WHI_OFF 0        // [NK][DIM][DIM] bf16 hi of W        (32768 B)
#define WLO_OFF 32768    // [NK][DIM][DIM] bf16 lo of W        (32768 B)
#define HH_OFF  65536    // [NK][DIM] bf16 hi of h*log2e       (1024 B)
#define HL_OFF  66560    // [NK][DIM] bf16 lo
#define GH_OFF  67584    // [NK][DIM] bf16 hi of (mu/s2)*log2e
#define GL_OFF  68608    // [NK][DIM] bf16 lo
#define CG_OFF  69632    // [NK] f32: log2(const_k) + sum(mu^2*h)*log2e

typedef __attribute__((address_space(1))) const unsigned int gu32;
typedef __attribute__((address_space(3))) unsigned int lu32;

// Truncation split: x ~= hi + lo keeping ~17 mantissa bits.
__device__ __forceinline__ void split2(float x, short* hi, short* lo) {
  unsigned u = __float_as_uint(x);
  *hi = (short)(u >> 16);
  float hf = __uint_as_float(u & 0xFFFF0000u);
  float l = x - hf;                       // exact residual
  *lo = (short)(__float_as_uint(l) >> 16);
}

__global__ __launch_bounds__(256) void gmm_setup_kernel(
    const float* __restrict__ mu, const float* __restrict__ logsigma,
    const float* __restrict__ W, char* __restrict__ ws)
{
  int i = blockIdx.x * 256 + threadIdx.x;
  short* whi = (short*)(ws + WHI_OFF);
  short* wlo = (short*)(ws + WLO_OFF);
  if (i < NK * DIM * DIM) split2(W[i], &whi[i], &wlo[i]);
  if (i < NK * DIM) {
    float s2 = __expf(2.0f * logsigma[i]);
    float h = (-0.5f / s2) * LOG2E;       // exp2 later (log2e folded)
    float g = (mu[i] / s2) * LOG2E;
    short a, b;
    split2(h, &a, &b);
    ((short*)(ws + HH_OFF))[i] = a; ((short*)(ws + HL_OFF))[i] = b;
    split2(g, &a, &b);
    ((short*)(ws + GH_OFF))[i] = a; ((short*)(ws + GL_OFF))[i] = b;
  }
  if (i < NK) {
    float acc = 0.0f;
    for (int d = 0; d < DIM; ++d) {
      float s2 = __expf(2.0f * logsigma[i * DIM + d]);
      float m  = mu[i * DIM + d];
      acc += m * m * (-0.5f / s2) * LOG2E - 0.5f * log2f(6.283185307179586f * s2);
    }
    ((float*)(ws + CG_OFF))[i] = acc;
  }
}

// One wave = 64 samples = 4 tiles of 16. mfma_f32_16x16x32_bf16:
//   A/B frag: row/col = lane%16, k = (lane/16)*8 + j
//   D: col = lane&15, row = (lane>>4)*4 + reg      [m89-verified]
// LDS: whi staged (32KB) + per-wave gate-weight transpose (16KB) = 48KB
//   -> 3 blocks/CU, 12 waves/CU. wlo stays global: 32KB hot region == L1 size.
__global__ __launch_bounds__(256, 3) void gmm_moe_kernel(
    const float* __restrict__ x,
    const float* __restrict__ bias,
    const char* __restrict__ ws,
    float* __restrict__ out)
{
  __shared__ char  lds_w[32768];          // linear copy of whi region
  __shared__ float lds_p[4][4][NK][16];   // [wave][tile][expert][sample]
  const int tid  = threadIdx.x;
  const int wid  = tid >> 6;
  const int lane = tid & 63;
  const int g = lane >> 4;                // k-chunk / row-group
  const int c = lane & 15;                // A-row (sample) & B-col index
  const int sbase = (blockIdx.x * 4 + wid) * 64;

  // ---- issue x loads for all 4 tiles first (HBM latency longest) ----
  float4 xa[4][2];
  #pragma unroll
  for (int t = 0; t < 4; ++t) {
    const float4* xp =
        (const float4*)(x + (size_t)(sbase + t * 16 + c) * DIM + g * 8);
    xa[t][0] = xp[0];
    xa[t][1] = xp[1];
  }

  // ---- gate tables (small, L2-hot) ----
  const bf16x8 fhh = ((const bf16x8*)(ws + HH_OFF))[c * 4 + g];
  const bf16x8 fhl = ((const bf16x8*)(ws + HL_OFF))[c * 4 + g];
  const bf16x8 fgh = ((const bf16x8*)(ws + GH_OFF))[c * 4 + g];
  const bf16x8 fgl = ((const bf16x8*)(ws + GL_OFF))[c * 4 + g];
  const float  cgv = ((const float*)(ws + CG_OFF))[c];

  // ---- stage whi (32KB) into LDS: wave wid owns [wid*8KB, +8KB) ----
  #pragma unroll
  for (int i = 0; i < 8; ++i) {
    int off = wid * 8192 + i * 1024;
    __builtin_amdgcn_global_load_lds(
        (gu32*)(ws + WHI_OFF + off + lane * 16),
        (lu32*)(lds_w + off), 16, 0, 0);
  }

  // ---- gate phase: exponent via split-bf16 MFMA, exp2, row-sum, normalize ----
  bf16x8 xh[4], xl[4];
  #pragma unroll
  for (int t = 0; t < 4; ++t) {
    float xv[8] = {xa[t][0].x, xa[t][0].y, xa[t][0].z, xa[t][0].w,
                   xa[t][1].x, xa[t][1].y, xa[t][1].z, xa[t][1].w};
    bf16x8 x2h, x2l;
    #pragma unroll
    for (int j = 0; j < 8; ++j) {
      short h_, l_;
      split2(xv[j], &h_, &l_);
      xh[t][j] = h_; xl[t][j] = l_;
      float q = xv[j] * xv[j];
      split2(q, &h_, &l_);
      x2h[j] = h_; x2l[j] = l_;
    }
    f32x4 e = {cgv, cgv, cgv, cgv};
    e = MFMA16(x2h,   fhh, e, 0, 0, 0);
    e = MFMA16(x2l,   fhh, e, 0, 0, 0);
    e = MFMA16(x2h,   fhl, e, 0, 0, 0);
    e = MFMA16(xh[t], fgh, e, 0, 0, 0);
    e = MFMA16(xl[t], fgh, e, 0, 0, 0);
    e = MFMA16(xh[t], fgl, e, 0, 0, 0);
    // e[r] = log2(p) for sample (g*4+r), expert c
    float pr[4], sr[4];
    #pragma unroll
    for (int r = 0; r < 4; ++r) {
      pr[r] = __builtin_amdgcn_exp2f(e[r]);
      float s = pr[r];
      s += __shfl_xor(s, 1, 64);
      s += __shfl_xor(s, 2, 64);
      s += __shfl_xor(s, 4, 64);
      s += __shfl_xor(s, 8, 64);          // sum over the 16 experts
      sr[r] = s;
    }
    f32x4 wv;
    #pragma unroll
    for (int r = 0; r < 4; ++r) wv[r] = pr[r] * __builtin_amdgcn_rcpf(sr[r]);
    *(f32x4*)&lds_p[wid][t][c][g * 4] = wv;   // transpose for k-loop reads
  }

  // barrier drains vmcnt(0) -> global_load_lds staging complete for all waves
  __syncthreads();

  // ---- expert loop: C = relu(x W_k^T + b_k), out += w_k * C ----
  const bf16x8* wlo = (const bf16x8*)(ws + WLO_OFF);
  f32x4 o0[4], o1[4];
  #pragma unroll
  for (int t = 0; t < 4; ++t) { o0[t] = (f32x4){0,0,0,0}; o1[t] = (f32x4){0,0,0,0}; }

  #pragma unroll
  for (int k = 0; k < NK; ++k) {
    const bf16x8 w0h = *(const bf16x8*)(lds_w + k * 2048 + c * 64 + g * 16);
    const bf16x8 w1h = *(const bf16x8*)(lds_w + k * 2048 + (16 + c) * 64 + g * 16);
    const bf16x8 w0l = wlo[(k * DIM +      c) * 4 + g];   // L1-resident (32KB)
    const bf16x8 w1l = wlo[(k * DIM + 16 + c) * 4 + g];
    const float b0 = bias[k * DIM + c];
    const float b1 = bias[k * DIM + 16 + c];
    #pragma unroll
    for (int t = 0; t < 4; ++t) {
      f32x4 s0 = {b0, b0, b0, b0}, s1 = {b1, b1, b1, b1};
      s0 = MFMA16(xh[t], w0h, s0, 0, 0, 0);
      s0 = MFMA16(xl[t], w0h, s0, 0, 0, 0);
      s0 = MFMA16(xh[t], w0l, s0, 0, 0, 0);
      s1 = MFMA16(xh[t], w1h, s1, 0, 0, 0);
      s1 = MFMA16(xl[t], w1h, s1, 0, 0, 0);
      s1 = MFMA16(xh[t], w1l, s1, 0, 0, 0);
      const f32x4 wv = *(const f32x4*)&lds_p[wid][t][k][g * 4];
      const f32x4 z = {0.0f, 0.0f, 0.0f, 0.0f};
      o0[t] = __builtin_elementwise_fma(wv, __builtin_elementwise_max(s0, z), o0[t]);
      o1[t] = __builtin_elementwise_fma(wv, __builtin_elementwise_max(s1, z), o1[t]);
    }
  }

  // ---- store: lane (g,c) holds rows g*4+r of each tile, cols c and c+16 ----
  #pragma unroll
  for (int t = 0; t < 4; ++t) {
    #pragma unroll
    for (int r = 0; r < 4; ++r) {
      size_t row = (size_t)(sbase + t * 16 + g * 4 + r);
      out[row * DIM + c]      = o0[t][r];
      out[row * DIM + 16 + c] = o1[t][r];
    }
  }
}

extern "C" void kernel_launch(void* const* d_in, const int* in_sizes, int n_in,
                              void* d_out, int out_size, void* d_ws, size_t ws_size,
                              hipStream_t stream) {
  const float* x  = (const float*)d_in[0];   // [B, DIM]
  const float* mu = (const float*)d_in[1];   // [NK, DIM]
  const float* ls = (const float*)d_in[2];   // [NK, DIM]
  const float* W  = (const float*)d_in[3];   // [NK, DIM, DIM]
  const float* bv = (const float*)d_in[4];   // [NK, DIM]
  float* out = (float*)d_out;
  const int B = in_sizes[0] / DIM;

  gmm_setup_kernel<<<(NK * DIM * DIM + 255) / 256, 256, 0, stream>>>(
      mu, ls, W, (char*)d_ws);
  gmm_moe_kernel<<<B / 256, 256, 0, stream>>>(x, bv, (const char*)d_ws, out);
}